// Round 13
// baseline (91.072 us; speedup 1.0000x reference)
//
#include <hip/hip_runtime.h>

typedef _Float16 half_t;
typedef __attribute__((ext_vector_type(8))) _Float16 half8;
typedef __attribute__((ext_vector_type(4))) float f32x4;
typedef __attribute__((ext_vector_type(8))) short short8v;
typedef unsigned short u16;
typedef unsigned int u32;

// Log2-domain scaled math (rounds 4/6/7/9/10/12 verified): E' = (1-cos)*SCALE.
// pE = 2^(15-E') (fp16, all normal), pv = 2^(v'-15) (f32); biases cancel.
#define SCALE_F     14.4269504f     /* 10*log2(e) */
#define INV_SCALE_F 0.0693147181f
#define C_MU       -9.99998523f     /* log2(1/1024+1e-8) */
#define C_NU       -9.99998523f
#define MU_F        0.000976572498f /* 2^C_MU */
#define ERR_STOP_B  1.44269504f     /* 0.1 * SCALE, per-batch stop */
#define MAX_ITER    100
#define SPIN_LIMIT  50000000LL
#define PV0         3.0517578125e-05f  /* 2^-15 */

#define SMEM_E   131072             /* 64*1024 fp16 pE */
#define SMEM_CP  4096               /* 1024 f32 swizzled col accumulator */
#define SMEM_PV  4096               /* 1024 f32 pv */
#define SMEM_RED 256
#define SMEM_TOTAL (SMEM_E + SMEM_CP + SMEM_PV + SMEM_RED)

#define PSTRIDE  1040               /* u32/slice: 1024 f32 cols + werr + pad */
#define PWORDS   (2*16*16*PSTRIDE)  /* parity-dbuf total = 532480 */

// bank-spreading bijection: for stride-8 bases, each add instruction hits
// all 32 banks once per 32 lanes (2 lanes/bank over wave64 = conflict-free)
#define SWZ(c) ((c) ^ (((c) >> 5) & 7))

__device__ __forceinline__ float fexp2(float x) { return __builtin_amdgcn_exp2f(x); }
__device__ __forceinline__ float flog2(float x) { return __builtin_amdgcn_logf(x); }
__device__ __forceinline__ float frcp(float x)  { return __builtin_amdgcn_rcpf(x); }

__device__ __forceinline__ u16 f2bf(float f) {
  unsigned u = __float_as_uint(f);
  return (u16)((u + 0x7fffu + ((u >> 16) & 1u)) >> 16);
}
__device__ __forceinline__ u32 agload(const u32* p) {
  return __hip_atomic_load(p, __ATOMIC_RELAXED, __HIP_MEMORY_SCOPE_AGENT);
}
__device__ __forceinline__ void agstore(u32* p, u32 v) {
  __hip_atomic_store(p, v, __ATOMIC_RELAXED, __HIP_MEMORY_SCOPE_AGENT);
}

// ---------------- K1: normalize x,y -> bf16 rows; zero per-call state ------
__global__ __launch_bounds__(256) void mfa_prep(const float* __restrict__ x,
                                                const float* __restrict__ y,
                                                u16* __restrict__ Xn,
                                                u16* __restrict__ Yn,
                                                u32* __restrict__ partials,
                                                float* __restrict__ cost) {
  int g = blockIdx.x * 256 + threadIdx.x;    // 65536 threads
  if (g < 16) cost[g] = 0.0f;
  #pragma unroll
  for (int j = 0; j < 9; ++j) {              // zero tagged partials (tag -> 0)
    int idx = (j << 16) + g;
    if (idx < PWORDS) partials[idx] = 0u;
  }

  int wid = g >> 6;                          // 0..1023 waves
  int lane = threadIdx.x & 63;
  for (int rr = 0; rr < 32; ++rr) {
    int row = wid + (rr << 10);              // 0..32767
    const float* src = (row < 16384) ? x + (size_t)row * 256
                                     : y + (size_t)(row - 16384) * 256;
    float4 xa = ((const float4*)src)[lane];
    float ss = xa.x*xa.x + xa.y*xa.y + xa.z*xa.z + xa.w*xa.w;
    #pragma unroll
    for (int off = 32; off; off >>= 1) ss += __shfl_xor(ss, off);
    float inv = 1.0f / fmaxf(sqrtf(ss), 1e-8f);
    ushort4 o;
    o.x = f2bf(xa.x * inv); o.y = f2bf(xa.y * inv);
    o.z = f2bf(xa.z * inv); o.w = f2bf(xa.w * inv);
    u16* dst = ((row < 16384) ? Xn + ((size_t)row << 8)
                              : Yn + ((size_t)(row - 16384) << 8)) + lane * 4;
    *(ushort4*)dst = o;
  }
}

// ---------------- K2: fused MFMA E-build + LDS-resident Sinkhorn ----------
// Plain launch, 256 blocks x 512 thr (2 waves/SIMD), 136 KB LDS -> 1 blk/CU.
// R12 base; col-reduce via swizzled ds_add_f32 (2 barriers/iter, no staging).
__global__ __launch_bounds__(512, 1) void mfa_sink_fused(
    const u16* __restrict__ Xn, const u16* __restrict__ Yn,
    u32* __restrict__ partials, float* __restrict__ cost) {
  extern __shared__ char smem[];
  half_t* pEls = (half_t*)smem;                               // [64][1024] pE
  float*  cpb  = (float*)(smem + SMEM_E);                     // [1024] swz acc
  float*  pvsh = (float*)(smem + SMEM_E + SMEM_CP);           // [1024] pv
  float*  sred = (float*)(smem + SMEM_E + SMEM_CP + SMEM_PV); // [8] + err slot

  const int t = threadIdx.x, w = t >> 6, lane = t & 63;
  const int lane15 = lane & 15, lgrp = lane >> 4;
  const int blk = blockIdx.x;
  const int b = ((blk & 7) << 1) | ((blk >> 7) & 1);   // XCD grouping heuristic
  const int k = (blk >> 3) & 15;

  // ---- build pE = 2^(15-E') (64 x 1024 fp16) in LDS via MFMA ----
  {
    const u16* Xb = Xn + ((size_t)((b << 10) + (k << 6)) << 8);  // 64 rows
    const u16* Yb = Yn + ((size_t)(b << 10) << 8);               // 1024 rows
    const int wcol = w << 7;                 // wave's 128-col slice
    #pragma unroll
    for (int pass = 0; pass < 2; ++pass) {
      const int c0 = wcol + (pass << 6);     // 64-col group
      f32x4 acc[4][4];
      #pragma unroll
      for (int i = 0; i < 4; ++i)
        #pragma unroll
        for (int j = 0; j < 4; ++j) acc[i][j] = (f32x4){0.f, 0.f, 0.f, 0.f};
      for (int ks = 0; ks < 8; ++ks) {
        const int koff = (ks << 5) + (lgrp << 3);
        short8v a[4], bb[4];
        #pragma unroll
        for (int i = 0; i < 4; ++i)
          a[i] = *(const short8v*)(Xb + (((i << 4) + lane15) << 8) + koff);
        #pragma unroll
        for (int j = 0; j < 4; ++j)
          bb[j] = *(const short8v*)(Yb + ((size_t)(c0 + (j << 4) + lane15) << 8) + koff);
        #pragma unroll
        for (int i = 0; i < 4; ++i)
          #pragma unroll
          for (int j = 0; j < 4; ++j)
            acc[i][j] = __builtin_amdgcn_mfma_f32_16x16x32_bf16(a[i], bb[j], acc[i][j], 0, 0, 0);
      }
      #pragma unroll
      for (int i = 0; i < 4; ++i)
        #pragma unroll
        for (int j = 0; j < 4; ++j) {
          const int col = c0 + (j << 4) + lane15;
          #pragma unroll
          for (int q = 0; q < 4; ++q) {
            const int row = (i << 4) + (lgrp << 2) + q;
            pEls[(row << 10) + col] =
                (half_t)fexp2(15.0f - (1.0f - acc[i][j][q]) * SCALE_F);
          }
        }
    }
  }
  pvsh[t] = PV0; pvsh[t + 512] = PV0;        // pv for v'=0
  cpb[t] = 0.0f; cpb[t + 512] = 0.0f;        // accumulator clean
  __syncthreads();

  float ureg[8];
  #pragma unroll
  for (int r = 0; r < 8; ++r) ureg[r] = 0.0f;
  float vr0 = 0.0f, vr1 = 0.0f;              // v' for cols t, t+512

  const int mlo = lane << 3;
  int it = 0;
  for (; it < MAX_ITER; ++it) {
    // ---- load pv for this lane's 16 cols ----
    const f32x4* p4 = (const f32x4*)pvsh;
    f32x4 a4 = p4[lane*2], b4 = p4[lane*2 + 1];
    f32x4 c4 = p4[128 + lane*2], d4 = p4[128 + lane*2 + 1];
    float pv[16];
    pv[0]=a4.x; pv[1]=a4.y; pv[2]=a4.z; pv[3]=a4.w;
    pv[4]=b4.x; pv[5]=b4.y; pv[6]=b4.z; pv[7]=b4.w;
    pv[8]=c4.x; pv[9]=c4.y; pv[10]=c4.z; pv[11]=c4.w;
    pv[12]=d4.x; pv[13]=d4.y; pv[14]=d4.z; pv[15]=d4.w;

    // ---- Phase A: all 8 row-sums ----
    half8 ea[8], eb[8];
    float s[8];
    #pragma unroll
    for (int r = 0; r < 8; ++r) {
      const half8* E8 = (const half8*)(pEls + (((w << 3) + r) << 10));
      ea[r] = E8[lane]; eb[r] = E8[lane + 64];
      float acc = 0.0f;
      #pragma unroll
      for (int j = 0; j < 8; ++j) acc = __builtin_fmaf(pv[j], (float)ea[r][j], acc);
      #pragma unroll
      for (int j = 0; j < 8; ++j) acc = __builtin_fmaf(pv[8+j], (float)eb[r][j], acc);
      s[r] = acc;
    }
    // ---- Phase B: batched butterfly (8-way ILP per stage) ----
    #pragma unroll
    for (int off = 32; off; off >>= 1) {
      #pragma unroll
      for (int r = 0; r < 8; ++r) s[r] += __shfl_xor(s[r], off);
    }
    // ---- Phase C: u updates ----
    float eu[8], werr = 0.0f;
    #pragma unroll
    for (int r = 0; r < 8; ++r) {
      float unew = C_MU - flog2(s[r]);
      eu[r] = MU_F * frcp(s[r]);             // 2^u'
      werr += fabsf(unew - ureg[r]);
      ureg[r] = unew;
    }
    if (lane == 0) sred[w] = werr;
    // ---- Phase D: col-partials, swizzled ds_add into cpb[1024] ----
    {
      float inner[16];
      #pragma unroll
      for (int j = 0; j < 16; ++j) inner[j] = 0.0f;
      #pragma unroll
      for (int r = 0; r < 8; ++r) {
        #pragma unroll
        for (int j = 0; j < 8; ++j)
          inner[j] = __builtin_fmaf((float)ea[r][j], eu[r], inner[j]);
        #pragma unroll
        for (int j = 0; j < 8; ++j)
          inner[8+j] = __builtin_fmaf((float)eb[r][j], eu[r], inner[8+j]);
      }
      #pragma unroll
      for (int j = 0; j < 8; ++j)
        atomicAdd(&cpb[SWZ(mlo + j)], inner[j] * pv[j]);
      #pragma unroll
      for (int j = 0; j < 8; ++j)
        atomicAdd(&cpb[SWZ(512 + mlo + j)], inner[8+j] * pv[8+j]);
    }
    __syncthreads();                         // barrier 1: adds + sred done

    // ---- publish tagged f32 col sums (cols t, t+512) + werr ----
    const int p = it & 1;
    const u32 tag = (u32)((it + 1) & 3);
    {
      u32* ps = partials + (size_t)((((p << 4) | b) << 4) | k) * PSTRIDE;
      float fa = cpb[SWZ(t)];
      float fb = cpb[SWZ(512 + t)];
      cpb[SWZ(t)] = 0.0f;                    // re-arm (owner thread; adds
      cpb[SWZ(512 + t)] = 0.0f;              //  resume only after barrier 2)
      agstore(&ps[t],       (__float_as_uint(fa) & ~3u) | tag);
      agstore(&ps[512 + t], (__float_as_uint(fb) & ~3u) | tag);
      if (t == 0) {
        float be = sred[0]+sred[1]+sred[2]+sred[3]+sred[4]+sred[5]+sred[6]+sred[7];
        agstore(&ps[1024], (__float_as_uint(be) & ~3u) | tag);
      }
    }

    // ---- tag-spin bulk read: retry whole batch, wave-uniform ----
    {
      const u32* pr = partials + (size_t)(((p << 4) | b) << 4) * PSTRIDE;
      u32 wa[16], wb[16], wwe = tag;
      long long tws = clock64();
      for (;;) {
        #pragma unroll
        for (int j = 0; j < 16; ++j) {
          wa[j] = agload(&pr[j * PSTRIDE + t]);
          wb[j] = agload(&pr[j * PSTRIDE + 512 + t]);
        }
        u32 diff = 0;
        #pragma unroll
        for (int j = 0; j < 16; ++j)
          diff |= ((wa[j] ^ tag) | (wb[j] ^ tag)) & 3u;
        if (w == 0 && lane < 16) {
          wwe = agload(&pr[lane * PSTRIDE + 1024]);
          diff |= (wwe ^ tag) & 3u;
        }
        if (__all(diff == 0)) break;
        if (clock64() - tws > SPIN_LIMIT) break;
      }
      float t0s = 0.0f, t1s = 0.0f;
      #pragma unroll
      for (int j = 0; j < 16; ++j) {
        t0s += __uint_as_float(wa[j] & ~3u);
        t1s += __uint_as_float(wb[j] & ~3u);
      }
      if (w == 0) {
        float we = __uint_as_float(wwe & ~3u);
        #pragma unroll
        for (int off = 8; off; off >>= 1) we += __shfl_xor(we, off);
        if (lane == 0) sred[8] = we;
      }
      vr0 += C_NU - flog2(t0s);
      vr1 += C_NU - flog2(t1s);
      pvsh[t]       = fexp2(vr0 - 15.0f);
      pvsh[t + 512] = fexp2(vr1 - 15.0f);
    }
    __syncthreads();                         // barrier 2: pv/cpb/err ready

    if (sred[8] < ERR_STOP_B) break;   // per-batch stop, update applied (ref freeze)
  }

  // ---- cost: sum pi*E'/SCALE, pi = 2^u' * pv * pE, E' = 15 - log2(pE) ----
  {
    const f32x4* p4 = (const f32x4*)pvsh;
    f32x4 a4 = p4[lane*2], b4 = p4[lane*2 + 1];
    f32x4 c4 = p4[128 + lane*2], d4 = p4[128 + lane*2 + 1];
    float pv[16];
    pv[0]=a4.x; pv[1]=a4.y; pv[2]=a4.z; pv[3]=a4.w;
    pv[4]=b4.x; pv[5]=b4.y; pv[6]=b4.z; pv[7]=b4.w;
    pv[8]=c4.x; pv[9]=c4.y; pv[10]=c4.z; pv[11]=c4.w;
    pv[12]=d4.x; pv[13]=d4.y; pv[14]=d4.z; pv[15]=d4.w;
    float cacc = 0.0f;
    #pragma unroll
    for (int r = 0; r < 8; ++r) {
      const half8* E8 = (const half8*)(pEls + (((w << 3) + r) << 10));
      half8 ea = E8[lane], eb = E8[lane + 64];
      float su = fexp2(ureg[r]);
      #pragma unroll
      for (int j = 0; j < 8; ++j) {
        float pe = (float)ea[j];
        float e = 15.0f - flog2(pe);
        cacc += su * pv[j] * pe * e;
      }
      #pragma unroll
      for (int j = 0; j < 8; ++j) {
        float pe = (float)eb[j];
        float e = 15.0f - flog2(pe);
        cacc += su * pv[8 + j] * pe * e;
      }
    }
    #pragma unroll
    for (int off = 32; off; off >>= 1) cacc += __shfl_xor(cacc, off);
    if (lane == 0) sred[w] = cacc;
    __syncthreads();
    if (t == 0)
      atomicAdd(&cost[b], (sred[0]+sred[1]+sred[2]+sred[3]+sred[4]+sred[5]+
                           sred[6]+sred[7]) * INV_SCALE_F);
  }
}

extern "C" void kernel_launch(void* const* d_in, const int* in_sizes, int n_in,
                              void* d_out, int out_size, void* d_ws, size_t ws_size,
                              hipStream_t stream) {
  const float* x = (const float*)d_in[0];
  const float* y = (const float*)d_in[1];
  float* cost = (float*)d_out;

  char* base = (char*)d_ws;
  u16* Xn       = (u16*)base;                          // 8 MB
  u16* Yn       = (u16*)(base + 8388608);              // 8 MB
  u32* partials = (u32*)(base + 16777216);             // 532480 u32 ~= 2.03 MB
  size_t needed = 16777216 + (size_t)PWORDS * 4;
  if (ws_size < needed) return;                        // ~18.8 MB needed

  mfa_prep<<<256, 256, 0, stream>>>(x, y, Xn, Yn, partials, cost);

  (void)hipFuncSetAttribute((const void*)mfa_sink_fused,
                            hipFuncAttributeMaxDynamicSharedMemorySize, SMEM_TOTAL);
  mfa_sink_fused<<<dim3(256), dim3(512), SMEM_TOTAL, stream>>>(
      Xn, Yn, partials, cost);
}

// Round 14
// 74.493 us; speedup vs baseline: 1.2226x; 1.2226x over previous
//
#include <hip/hip_runtime.h>

typedef _Float16 half_t;
typedef __attribute__((ext_vector_type(8))) _Float16 half8;
typedef __attribute__((ext_vector_type(4))) float f32x4;
typedef __attribute__((ext_vector_type(8))) short short8v;
typedef unsigned short u16;
typedef unsigned int u32;

// Log2-domain scaled math (rounds 4/6/7/9/10/12 verified): E' = (1-cos)*SCALE.
// pE = 2^(15-E') (fp16, all normal), pv = 2^(v'-15) (f32); biases cancel.
#define SCALE_F     14.4269504f     /* 10*log2(e) */
#define INV_SCALE_F 0.0693147181f
#define C_MU       -9.99998523f     /* log2(1/1024+1e-8) */
#define C_NU       -9.99998523f
#define MU_F        0.000976572498f /* 2^C_MU */
#define ERR_STOP_B  1.44269504f     /* 0.1 * SCALE, per-batch stop */
#define MAX_ITER    100
#define SPIN_LIMIT  50000000LL
#define PV0         3.0517578125e-05f  /* 2^-15 */

#define SMEM_E   131072             /* 64*1024 fp16 pE (build staging only) */
#define SMEM_CP  16384              /* 4*1024 f32 col-reduce */
#define SMEM_PV  4096               /* 1024 f32 pv */
#define SMEM_RED 256
#define SMEM_TOTAL (SMEM_E + SMEM_CP + SMEM_PV + SMEM_RED)

#define PSTRIDE  1040               /* u32/slice: 1024 f32 cols + werr + pad */
#define PWORDS   (2*16*16*PSTRIDE)  /* parity-dbuf total = 532480 */

__device__ __forceinline__ float fexp2(float x) { return __builtin_amdgcn_exp2f(x); }
__device__ __forceinline__ float flog2(float x) { return __builtin_amdgcn_logf(x); }
__device__ __forceinline__ float frcp(float x)  { return __builtin_amdgcn_rcpf(x); }

__device__ __forceinline__ u16 f2bf(float f) {
  unsigned u = __float_as_uint(f);
  return (u16)((u + 0x7fffu + ((u >> 16) & 1u)) >> 16);
}
__device__ __forceinline__ u32 agload(const u32* p) {
  return __hip_atomic_load(p, __ATOMIC_RELAXED, __HIP_MEMORY_SCOPE_AGENT);
}
__device__ __forceinline__ void agstore(u32* p, u32 v) {
  __hip_atomic_store(p, v, __ATOMIC_RELAXED, __HIP_MEMORY_SCOPE_AGENT);
}

// ---------------- K1: normalize x,y -> bf16 rows; zero per-call state ------
__global__ __launch_bounds__(256) void mfa_prep(const float* __restrict__ x,
                                                const float* __restrict__ y,
                                                u16* __restrict__ Xn,
                                                u16* __restrict__ Yn,
                                                u32* __restrict__ partials,
                                                float* __restrict__ cost) {
  int g = blockIdx.x * 256 + threadIdx.x;    // 65536 threads
  if (g < 16) cost[g] = 0.0f;
  #pragma unroll
  for (int j = 0; j < 9; ++j) {              // zero tagged partials (tag -> 0)
    int idx = (j << 16) + g;
    if (idx < PWORDS) partials[idx] = 0u;
  }

  int wid = g >> 6;                          // 0..1023 waves
  int lane = threadIdx.x & 63;
  for (int rr = 0; rr < 32; ++rr) {
    int row = wid + (rr << 10);              // 0..32767
    const float* src = (row < 16384) ? x + (size_t)row * 256
                                     : y + (size_t)(row - 16384) * 256;
    float4 xa = ((const float4*)src)[lane];
    float ss = xa.x*xa.x + xa.y*xa.y + xa.z*xa.z + xa.w*xa.w;
    #pragma unroll
    for (int off = 32; off; off >>= 1) ss += __shfl_xor(ss, off);
    float inv = 1.0f / fmaxf(sqrtf(ss), 1e-8f);
    ushort4 o;
    o.x = f2bf(xa.x * inv); o.y = f2bf(xa.y * inv);
    o.z = f2bf(xa.z * inv); o.w = f2bf(xa.w * inv);
    u16* dst = ((row < 16384) ? Xn + ((size_t)row << 8)
                              : Yn + ((size_t)(row - 16384) << 8)) + lane * 4;
    *(ushort4*)dst = o;
  }
}

// ---------------- K2: fused MFMA E-build + register-resident Sinkhorn -----
// Plain launch, 256 blocks x 512 thr (2 waves/SIMD), 148 KB LDS -> 1 blk/CU.
// R12 base; pE is loaded into registers ONCE after the build and the
// iteration loop + cost pass never touch pEls again (kills the dominant
// 256 KB/iter LDS streaming term).
__global__ __launch_bounds__(512, 1) void mfa_sink_fused(
    const u16* __restrict__ Xn, const u16* __restrict__ Yn,
    u32* __restrict__ partials, float* __restrict__ cost) {
  extern __shared__ char smem[];
  half_t* pEls = (half_t*)smem;                               // [64][1024] pE
  float*  cpb  = (float*)(smem + SMEM_E);                     // [4][1024]
  float*  pvsh = (float*)(smem + SMEM_E + SMEM_CP);           // [1024] pv
  float*  sred = (float*)(smem + SMEM_E + SMEM_CP + SMEM_PV); // [8] + err slot

  const int t = threadIdx.x, w = t >> 6, lane = t & 63;
  const int lane15 = lane & 15, lgrp = lane >> 4;
  const int blk = blockIdx.x;
  const int b = ((blk & 7) << 1) | ((blk >> 7) & 1);   // XCD grouping heuristic
  const int k = (blk >> 3) & 15;

  // ---- build pE = 2^(15-E') (64 x 1024 fp16) in LDS via MFMA ----
  {
    const u16* Xb = Xn + ((size_t)((b << 10) + (k << 6)) << 8);  // 64 rows
    const u16* Yb = Yn + ((size_t)(b << 10) << 8);               // 1024 rows
    const int wcol = w << 7;                 // wave's 128-col slice
    #pragma unroll
    for (int pass = 0; pass < 2; ++pass) {
      const int c0 = wcol + (pass << 6);     // 64-col group
      f32x4 acc[4][4];
      #pragma unroll
      for (int i = 0; i < 4; ++i)
        #pragma unroll
        for (int j = 0; j < 4; ++j) acc[i][j] = (f32x4){0.f, 0.f, 0.f, 0.f};
      for (int ks = 0; ks < 8; ++ks) {
        const int koff = (ks << 5) + (lgrp << 3);
        short8v a[4], bb[4];
        #pragma unroll
        for (int i = 0; i < 4; ++i)
          a[i] = *(const short8v*)(Xb + (((i << 4) + lane15) << 8) + koff);
        #pragma unroll
        for (int j = 0; j < 4; ++j)
          bb[j] = *(const short8v*)(Yb + ((size_t)(c0 + (j << 4) + lane15) << 8) + koff);
        #pragma unroll
        for (int i = 0; i < 4; ++i)
          #pragma unroll
          for (int j = 0; j < 4; ++j)
            acc[i][j] = __builtin_amdgcn_mfma_f32_16x16x32_bf16(a[i], bb[j], acc[i][j], 0, 0, 0);
      }
      #pragma unroll
      for (int i = 0; i < 4; ++i)
        #pragma unroll
        for (int j = 0; j < 4; ++j) {
          const int col = c0 + (j << 4) + lane15;
          #pragma unroll
          for (int q = 0; q < 4; ++q) {
            const int row = (i << 4) + (lgrp << 2) + q;
            pEls[(row << 10) + col] =
                (half_t)fexp2(15.0f - (1.0f - acc[i][j][q]) * SCALE_F);
          }
        }
    }
  }
  pvsh[t] = PV0; pvsh[t + 512] = PV0;        // pv for v'=0
  __syncthreads();

  // ---- load pE into registers ONCE (64 VGPRs); loop never reads pEls ----
  half8 ea[8], eb[8];
  #pragma unroll
  for (int r = 0; r < 8; ++r) {
    const half8* E8 = (const half8*)(pEls + (((w << 3) + r) << 10));
    ea[r] = E8[lane]; eb[r] = E8[lane + 64];
  }

  float ureg[8];
  #pragma unroll
  for (int r = 0; r < 8; ++r) ureg[r] = 0.0f;
  float vr0 = 0.0f, vr1 = 0.0f;              // v' for cols t, t+512

  const int mlo = lane << 3;
  int it = 0;
  for (; it < MAX_ITER; ++it) {
    // ---- load pv for this lane's 16 cols ----
    const f32x4* p4 = (const f32x4*)pvsh;
    f32x4 a4 = p4[lane*2], b4 = p4[lane*2 + 1];
    f32x4 c4 = p4[128 + lane*2], d4 = p4[128 + lane*2 + 1];
    float pv[16];
    pv[0]=a4.x; pv[1]=a4.y; pv[2]=a4.z; pv[3]=a4.w;
    pv[4]=b4.x; pv[5]=b4.y; pv[6]=b4.z; pv[7]=b4.w;
    pv[8]=c4.x; pv[9]=c4.y; pv[10]=c4.z; pv[11]=c4.w;
    pv[12]=d4.x; pv[13]=d4.y; pv[14]=d4.z; pv[15]=d4.w;

    // ---- Phase A: all 8 row-sums (from registers) ----
    float s[8];
    #pragma unroll
    for (int r = 0; r < 8; ++r) {
      float acc = 0.0f;
      #pragma unroll
      for (int j = 0; j < 8; ++j) acc = __builtin_fmaf(pv[j], (float)ea[r][j], acc);
      #pragma unroll
      for (int j = 0; j < 8; ++j) acc = __builtin_fmaf(pv[8+j], (float)eb[r][j], acc);
      s[r] = acc;
    }
    // ---- Phase B: batched butterfly (8-way ILP per stage) ----
    #pragma unroll
    for (int off = 32; off; off >>= 1) {
      #pragma unroll
      for (int r = 0; r < 8; ++r) s[r] += __shfl_xor(s[r], off);
    }
    // ---- Phase C: u updates (8 logs/rcps together) ----
    float eu[8], werr = 0.0f;
    #pragma unroll
    for (int r = 0; r < 8; ++r) {
      float unew = C_MU - flog2(s[r]);
      eu[r] = MU_F * frcp(s[r]);             // 2^u'
      werr += fabsf(unew - ureg[r]);
      ureg[r] = unew;
    }
    if (lane == 0) sred[w] = werr;
    // ---- Phase D: col-partial accumulation (from registers) ----
    float inner[16];
    #pragma unroll
    for (int j = 0; j < 16; ++j) inner[j] = 0.0f;
    #pragma unroll
    for (int r = 0; r < 8; ++r) {
      #pragma unroll
      for (int j = 0; j < 8; ++j)
        inner[j] = __builtin_fmaf((float)ea[r][j], eu[r], inner[j]);
      #pragma unroll
      for (int j = 0; j < 8; ++j)
        inner[8+j] = __builtin_fmaf((float)eb[r][j], eu[r], inner[8+j]);
    }
    float colacc[16];
    #pragma unroll
    for (int j = 0; j < 16; ++j) colacc[j] = inner[j] * pv[j];

    // ---- 8-wave col reduce via cpb[4][1024] ----
    if (w < 4) {
      #pragma unroll
      for (int j = 0; j < 4; ++j) {
        *(f32x4*)&cpb[w*1024 + mlo + 4*j - ((j>=2)?8:0) + ((j>=2)?512:0)] =
            (f32x4){colacc[4*j], colacc[4*j+1], colacc[4*j+2], colacc[4*j+3]};
      }
    }
    __syncthreads();
    if (w >= 4) {
      const int wb = (w - 4) * 1024;
      #pragma unroll
      for (int j = 0; j < 8; ++j) cpb[wb + mlo + j] += colacc[j];
      #pragma unroll
      for (int j = 0; j < 8; ++j) cpb[wb + 512 + mlo + j] += colacc[8 + j];
    }
    __syncthreads();

    // ---- publish tagged f32 col sums (cols t, t+512) + werr ----
    const int p = it & 1;
    const u32 tag = (u32)((it + 1) & 3);
    {
      u32* ps = partials + (size_t)((((p << 4) | b) << 4) | k) * PSTRIDE;
      float fa = cpb[t] + cpb[1024 + t] + cpb[2048 + t] + cpb[3072 + t];
      float fb = cpb[512 + t] + cpb[1536 + t] + cpb[2560 + t] + cpb[3584 + t];
      agstore(&ps[t],       (__float_as_uint(fa) & ~3u) | tag);
      agstore(&ps[512 + t], (__float_as_uint(fb) & ~3u) | tag);
      if (t == 0) {
        float be = sred[0]+sred[1]+sred[2]+sred[3]+sred[4]+sred[5]+sred[6]+sred[7];
        agstore(&ps[1024], (__float_as_uint(be) & ~3u) | tag);
      }
    }

    // ---- tag-spin bulk read: retry whole batch, wave-uniform ----
    {
      const u32* pr = partials + (size_t)(((p << 4) | b) << 4) * PSTRIDE;
      u32 wa[16], wb[16], wwe = tag;
      long long tws = clock64();
      for (;;) {
        #pragma unroll
        for (int j = 0; j < 16; ++j) {
          wa[j] = agload(&pr[j * PSTRIDE + t]);
          wb[j] = agload(&pr[j * PSTRIDE + 512 + t]);
        }
        u32 diff = 0;
        #pragma unroll
        for (int j = 0; j < 16; ++j)
          diff |= ((wa[j] ^ tag) | (wb[j] ^ tag)) & 3u;
        if (w == 0 && lane < 16) {
          wwe = agload(&pr[lane * PSTRIDE + 1024]);
          diff |= (wwe ^ tag) & 3u;
        }
        if (__all(diff == 0)) break;
        if (clock64() - tws > SPIN_LIMIT) break;
      }
      float t0s = 0.0f, t1s = 0.0f;
      #pragma unroll
      for (int j = 0; j < 16; ++j) {
        t0s += __uint_as_float(wa[j] & ~3u);
        t1s += __uint_as_float(wb[j] & ~3u);
      }
      if (w == 0) {
        float we = __uint_as_float(wwe & ~3u);
        #pragma unroll
        for (int off = 8; off; off >>= 1) we += __shfl_xor(we, off);
        if (lane == 0) sred[8] = we;
      }
      vr0 += C_NU - flog2(t0s);
      vr1 += C_NU - flog2(t1s);
      pvsh[t]       = fexp2(vr0 - 15.0f);
      pvsh[t + 512] = fexp2(vr1 - 15.0f);
    }
    __syncthreads();

    if (sred[8] < ERR_STOP_B) break;   // per-batch stop, update applied (ref freeze)
  }

  // ---- cost: sum pi*E'/SCALE, pi = 2^u' * pv * pE (all from registers) ----
  {
    const f32x4* p4 = (const f32x4*)pvsh;
    f32x4 a4 = p4[lane*2], b4 = p4[lane*2 + 1];
    f32x4 c4 = p4[128 + lane*2], d4 = p4[128 + lane*2 + 1];
    float pv[16];
    pv[0]=a4.x; pv[1]=a4.y; pv[2]=a4.z; pv[3]=a4.w;
    pv[4]=b4.x; pv[5]=b4.y; pv[6]=b4.z; pv[7]=b4.w;
    pv[8]=c4.x; pv[9]=c4.y; pv[10]=c4.z; pv[11]=c4.w;
    pv[12]=d4.x; pv[13]=d4.y; pv[14]=d4.z; pv[15]=d4.w;
    float cacc = 0.0f;
    #pragma unroll
    for (int r = 0; r < 8; ++r) {
      float su = fexp2(ureg[r]);
      #pragma unroll
      for (int j = 0; j < 8; ++j) {
        float pe = (float)ea[r][j];
        float e = 15.0f - flog2(pe);
        cacc += su * pv[j] * pe * e;
      }
      #pragma unroll
      for (int j = 0; j < 8; ++j) {
        float pe = (float)eb[r][j];
        float e = 15.0f - flog2(pe);
        cacc += su * pv[8 + j] * pe * e;
      }
    }
    #pragma unroll
    for (int off = 32; off; off >>= 1) cacc += __shfl_xor(cacc, off);
    if (lane == 0) sred[w] = cacc;
    __syncthreads();
    if (t == 0)
      atomicAdd(&cost[b], (sred[0]+sred[1]+sred[2]+sred[3]+sred[4]+sred[5]+
                           sred[6]+sred[7]) * INV_SCALE_F);
  }
}

extern "C" void kernel_launch(void* const* d_in, const int* in_sizes, int n_in,
                              void* d_out, int out_size, void* d_ws, size_t ws_size,
                              hipStream_t stream) {
  const float* x = (const float*)d_in[0];
  const float* y = (const float*)d_in[1];
  float* cost = (float*)d_out;

  char* base = (char*)d_ws;
  u16* Xn       = (u16*)base;                          // 8 MB
  u16* Yn       = (u16*)(base + 8388608);              // 8 MB
  u32* partials = (u32*)(base + 16777216);             // 532480 u32 ~= 2.03 MB
  size_t needed = 16777216 + (size_t)PWORDS * 4;
  if (ws_size < needed) return;                        // ~18.8 MB needed

  mfa_prep<<<256, 256, 0, stream>>>(x, y, Xn, Yn, partials, cost);

  (void)hipFuncSetAttribute((const void*)mfa_sink_fused,
                            hipFuncAttributeMaxDynamicSharedMemorySize, SMEM_TOTAL);
  mfa_sink_fused<<<dim3(256), dim3(512), SMEM_TOTAL, stream>>>(
      Xn, Yn, partials, cost);
}

// Round 15
// 73.646 us; speedup vs baseline: 1.2366x; 1.0115x over previous
//
#include <hip/hip_runtime.h>

typedef _Float16 half_t;
typedef __attribute__((ext_vector_type(8))) _Float16 half8;
typedef __attribute__((ext_vector_type(4))) float f32x4;
typedef __attribute__((ext_vector_type(8))) short short8v;
typedef unsigned short u16;
typedef unsigned int u32;

// Log2-domain scaled math (rounds 4/6/7/9/10/12 verified): E' = (1-cos)*SCALE.
// pE = 2^(15-E') (fp16, all normal), pv = 2^(v'-15) (f32); biases cancel.
#define SCALE_F     14.4269504f     /* 10*log2(e) */
#define INV_SCALE_F 0.0693147181f
#define C_MU       -9.99998523f     /* log2(1/1024+1e-8) */
#define C_NU       -9.99998523f
#define MU_F        0.000976572498f /* 2^C_MU */
#define ERR_STOP_B  1.44269504f     /* 0.1 * SCALE, per-batch stop */
#define MAX_ITER    100
#define SPIN_LIMIT  50000000LL
#define PV0         3.0517578125e-05f  /* 2^-15 */

#define SMEM_E   131072             /* 64*1024 fp16 pE (build staging only) */
#define SMEM_CP  16384              /* 4*1024 f32 col-reduce */
#define SMEM_PV  4096               /* 1024 f32 pv */
#define SMEM_RED 256
#define SMEM_TOTAL (SMEM_E + SMEM_CP + SMEM_PV + SMEM_RED)

#define PSTRIDE  1040               /* u32/slice: 1024 f32 cols + werr + pad */
#define PWORDS   (2*16*16*PSTRIDE)  /* parity-dbuf total = 532480 */

__device__ __forceinline__ float fexp2(float x) { return __builtin_amdgcn_exp2f(x); }
__device__ __forceinline__ float flog2(float x) { return __builtin_amdgcn_logf(x); }
__device__ __forceinline__ float frcp(float x)  { return __builtin_amdgcn_rcpf(x); }

__device__ __forceinline__ u16 f2bf(float f) {
  unsigned u = __float_as_uint(f);
  return (u16)((u + 0x7fffu + ((u >> 16) & 1u)) >> 16);
}
__device__ __forceinline__ u32 agload(const u32* p) {
  return __hip_atomic_load(p, __ATOMIC_RELAXED, __HIP_MEMORY_SCOPE_AGENT);
}
__device__ __forceinline__ void agstore(u32* p, u32 v) {
  __hip_atomic_store(p, v, __ATOMIC_RELAXED, __HIP_MEMORY_SCOPE_AGENT);
}

// ---------------- K1: normalize x,y -> bf16 rows; zero per-call state ------
__global__ __launch_bounds__(256) void mfa_prep(const float* __restrict__ x,
                                                const float* __restrict__ y,
                                                u16* __restrict__ Xn,
                                                u16* __restrict__ Yn,
                                                u32* __restrict__ partials,
                                                float* __restrict__ cost) {
  int g = blockIdx.x * 256 + threadIdx.x;    // 65536 threads
  if (g < 16) cost[g] = 0.0f;
  #pragma unroll
  for (int j = 0; j < 9; ++j) {              // zero tagged partials (tag -> 0)
    int idx = (j << 16) + g;
    if (idx < PWORDS) partials[idx] = 0u;
  }

  int wid = g >> 6;                          // 0..1023 waves
  int lane = threadIdx.x & 63;
  for (int rr = 0; rr < 32; ++rr) {
    int row = wid + (rr << 10);              // 0..32767
    const float* src = (row < 16384) ? x + (size_t)row * 256
                                     : y + (size_t)(row - 16384) * 256;
    float4 xa = ((const float4*)src)[lane];
    float ss = xa.x*xa.x + xa.y*xa.y + xa.z*xa.z + xa.w*xa.w;
    #pragma unroll
    for (int off = 32; off; off >>= 1) ss += __shfl_xor(ss, off);
    float inv = 1.0f / fmaxf(sqrtf(ss), 1e-8f);
    ushort4 o;
    o.x = f2bf(xa.x * inv); o.y = f2bf(xa.y * inv);
    o.z = f2bf(xa.z * inv); o.w = f2bf(xa.w * inv);
    u16* dst = ((row < 16384) ? Xn + ((size_t)row << 8)
                              : Yn + ((size_t)(row - 16384) << 8)) + lane * 4;
    *(ushort4*)dst = o;
  }
}

// ---------------- K2: fused MFMA E-build + register-resident Sinkhorn -----
// Plain launch, 256 blocks x 512 thr, 148 KB LDS -> 1 blk/CU = 2 waves/EU.
// waves_per_eu(2,2) tells the allocator the TRUE occupancy ceiling (LDS-
// capped), unlocking 256 VGPRs so ea/eb stay register-resident for the
// whole loop (R14's version was silently rematerialized from LDS at
// VGPR=128 — SQ_LDS_BANK_CONFLICT identical to R12 proved it).
__global__ __attribute__((amdgpu_flat_work_group_size(512, 512),
                          amdgpu_waves_per_eu(2, 2)))
void mfa_sink_fused(
    const u16* __restrict__ Xn, const u16* __restrict__ Yn,
    u32* __restrict__ partials, float* __restrict__ cost) {
  extern __shared__ char smem[];
  half_t* pEls = (half_t*)smem;                               // [64][1024] pE
  float*  cpb  = (float*)(smem + SMEM_E);                     // [4][1024]
  float*  pvsh = (float*)(smem + SMEM_E + SMEM_CP);           // [1024] pv
  float*  sred = (float*)(smem + SMEM_E + SMEM_CP + SMEM_PV); // [8] + err slot

  const int t = threadIdx.x, w = t >> 6, lane = t & 63;
  const int lane15 = lane & 15, lgrp = lane >> 4;
  const int blk = blockIdx.x;
  const int b = ((blk & 7) << 1) | ((blk >> 7) & 1);   // XCD grouping heuristic
  const int k = (blk >> 3) & 15;

  // ---- build pE = 2^(15-E') (64 x 1024 fp16) in LDS via MFMA ----
  {
    const u16* Xb = Xn + ((size_t)((b << 10) + (k << 6)) << 8);  // 64 rows
    const u16* Yb = Yn + ((size_t)(b << 10) << 8);               // 1024 rows
    const int wcol = w << 7;                 // wave's 128-col slice
    #pragma unroll
    for (int pass = 0; pass < 2; ++pass) {
      const int c0 = wcol + (pass << 6);     // 64-col group
      f32x4 acc[4][4];
      #pragma unroll
      for (int i = 0; i < 4; ++i)
        #pragma unroll
        for (int j = 0; j < 4; ++j) acc[i][j] = (f32x4){0.f, 0.f, 0.f, 0.f};
      for (int ks = 0; ks < 8; ++ks) {
        const int koff = (ks << 5) + (lgrp << 3);
        short8v a[4], bb[4];
        #pragma unroll
        for (int i = 0; i < 4; ++i)
          a[i] = *(const short8v*)(Xb + (((i << 4) + lane15) << 8) + koff);
        #pragma unroll
        for (int j = 0; j < 4; ++j)
          bb[j] = *(const short8v*)(Yb + ((size_t)(c0 + (j << 4) + lane15) << 8) + koff);
        #pragma unroll
        for (int i = 0; i < 4; ++i)
          #pragma unroll
          for (int j = 0; j < 4; ++j)
            acc[i][j] = __builtin_amdgcn_mfma_f32_16x16x32_bf16(a[i], bb[j], acc[i][j], 0, 0, 0);
      }
      #pragma unroll
      for (int i = 0; i < 4; ++i)
        #pragma unroll
        for (int j = 0; j < 4; ++j) {
          const int col = c0 + (j << 4) + lane15;
          #pragma unroll
          for (int q = 0; q < 4; ++q) {
            const int row = (i << 4) + (lgrp << 2) + q;
            pEls[(row << 10) + col] =
                (half_t)fexp2(15.0f - (1.0f - acc[i][j][q]) * SCALE_F);
          }
        }
    }
  }
  pvsh[t] = PV0; pvsh[t + 512] = PV0;        // pv for v'=0
  __syncthreads();

  // ---- load pE into registers ONCE (64 VGPRs); loop never reads pEls ----
  half8 ea[8], eb[8];
  #pragma unroll
  for (int r = 0; r < 8; ++r) {
    const half8* E8 = (const half8*)(pEls + (((w << 3) + r) << 10));
    ea[r] = E8[lane]; eb[r] = E8[lane + 64];
  }

  float ureg[8];
  #pragma unroll
  for (int r = 0; r < 8; ++r) ureg[r] = 0.0f;
  float vr0 = 0.0f, vr1 = 0.0f;              // v' for cols t, t+512

  const int mlo = lane << 3;
  int it = 0;
  for (; it < MAX_ITER; ++it) {
    // ---- load pv for this lane's 16 cols ----
    const f32x4* p4 = (const f32x4*)pvsh;
    f32x4 a4 = p4[lane*2], b4 = p4[lane*2 + 1];
    f32x4 c4 = p4[128 + lane*2], d4 = p4[128 + lane*2 + 1];
    float pv[16];
    pv[0]=a4.x; pv[1]=a4.y; pv[2]=a4.z; pv[3]=a4.w;
    pv[4]=b4.x; pv[5]=b4.y; pv[6]=b4.z; pv[7]=b4.w;
    pv[8]=c4.x; pv[9]=c4.y; pv[10]=c4.z; pv[11]=c4.w;
    pv[12]=d4.x; pv[13]=d4.y; pv[14]=d4.z; pv[15]=d4.w;

    // ---- Phase A: all 8 row-sums (from registers) ----
    float s[8];
    #pragma unroll
    for (int r = 0; r < 8; ++r) {
      float acc = 0.0f;
      #pragma unroll
      for (int j = 0; j < 8; ++j) acc = __builtin_fmaf(pv[j], (float)ea[r][j], acc);
      #pragma unroll
      for (int j = 0; j < 8; ++j) acc = __builtin_fmaf(pv[8+j], (float)eb[r][j], acc);
      s[r] = acc;
    }
    // ---- Phase B: batched butterfly (8-way ILP per stage) ----
    #pragma unroll
    for (int off = 32; off; off >>= 1) {
      #pragma unroll
      for (int r = 0; r < 8; ++r) s[r] += __shfl_xor(s[r], off);
    }
    // ---- Phase C: u updates (8 logs/rcps together) ----
    float eu[8], werr = 0.0f;
    #pragma unroll
    for (int r = 0; r < 8; ++r) {
      float unew = C_MU - flog2(s[r]);
      eu[r] = MU_F * frcp(s[r]);             // 2^u'
      werr += fabsf(unew - ureg[r]);
      ureg[r] = unew;
    }
    if (lane == 0) sred[w] = werr;
    // ---- Phase D: col-partial accumulation (from registers) ----
    float inner[16];
    #pragma unroll
    for (int j = 0; j < 16; ++j) inner[j] = 0.0f;
    #pragma unroll
    for (int r = 0; r < 8; ++r) {
      #pragma unroll
      for (int j = 0; j < 8; ++j)
        inner[j] = __builtin_fmaf((float)ea[r][j], eu[r], inner[j]);
      #pragma unroll
      for (int j = 0; j < 8; ++j)
        inner[8+j] = __builtin_fmaf((float)eb[r][j], eu[r], inner[8+j]);
    }
    float colacc[16];
    #pragma unroll
    for (int j = 0; j < 16; ++j) colacc[j] = inner[j] * pv[j];

    // ---- 8-wave col reduce via cpb[4][1024] ----
    if (w < 4) {
      #pragma unroll
      for (int j = 0; j < 4; ++j) {
        *(f32x4*)&cpb[w*1024 + mlo + 4*j - ((j>=2)?8:0) + ((j>=2)?512:0)] =
            (f32x4){colacc[4*j], colacc[4*j+1], colacc[4*j+2], colacc[4*j+3]};
      }
    }
    __syncthreads();
    if (w >= 4) {
      const int wb = (w - 4) * 1024;
      #pragma unroll
      for (int j = 0; j < 8; ++j) cpb[wb + mlo + j] += colacc[j];
      #pragma unroll
      for (int j = 0; j < 8; ++j) cpb[wb + 512 + mlo + j] += colacc[8 + j];
    }
    __syncthreads();

    // ---- publish tagged f32 col sums (cols t, t+512) + werr ----
    const int p = it & 1;
    const u32 tag = (u32)((it + 1) & 3);
    {
      u32* ps = partials + (size_t)((((p << 4) | b) << 4) | k) * PSTRIDE;
      float fa = cpb[t] + cpb[1024 + t] + cpb[2048 + t] + cpb[3072 + t];
      float fb = cpb[512 + t] + cpb[1536 + t] + cpb[2560 + t] + cpb[3584 + t];
      agstore(&ps[t],       (__float_as_uint(fa) & ~3u) | tag);
      agstore(&ps[512 + t], (__float_as_uint(fb) & ~3u) | tag);
      if (t == 0) {
        float be = sred[0]+sred[1]+sred[2]+sred[3]+sred[4]+sred[5]+sred[6]+sred[7];
        agstore(&ps[1024], (__float_as_uint(be) & ~3u) | tag);
      }
    }

    // ---- tag-spin bulk read: retry whole batch, wave-uniform ----
    {
      const u32* pr = partials + (size_t)(((p << 4) | b) << 4) * PSTRIDE;
      u32 wa[16], wb[16], wwe = tag;
      long long tws = clock64();
      for (;;) {
        #pragma unroll
        for (int j = 0; j < 16; ++j) {
          wa[j] = agload(&pr[j * PSTRIDE + t]);
          wb[j] = agload(&pr[j * PSTRIDE + 512 + t]);
        }
        u32 diff = 0;
        #pragma unroll
        for (int j = 0; j < 16; ++j)
          diff |= ((wa[j] ^ tag) | (wb[j] ^ tag)) & 3u;
        if (w == 0 && lane < 16) {
          wwe = agload(&pr[lane * PSTRIDE + 1024]);
          diff |= (wwe ^ tag) & 3u;
        }
        if (__all(diff == 0)) break;
        if (clock64() - tws > SPIN_LIMIT) break;
      }
      float t0s = 0.0f, t1s = 0.0f;
      #pragma unroll
      for (int j = 0; j < 16; ++j) {
        t0s += __uint_as_float(wa[j] & ~3u);
        t1s += __uint_as_float(wb[j] & ~3u);
      }
      if (w == 0) {
        float we = __uint_as_float(wwe & ~3u);
        #pragma unroll
        for (int off = 8; off; off >>= 1) we += __shfl_xor(we, off);
        if (lane == 0) sred[8] = we;
      }
      vr0 += C_NU - flog2(t0s);
      vr1 += C_NU - flog2(t1s);
      pvsh[t]       = fexp2(vr0 - 15.0f);
      pvsh[t + 512] = fexp2(vr1 - 15.0f);
    }
    __syncthreads();

    if (sred[8] < ERR_STOP_B) break;   // per-batch stop, update applied (ref freeze)
  }

  // ---- cost: sum pi*E'/SCALE, pi = 2^u' * pv * pE (all from registers) ----
  {
    const f32x4* p4 = (const f32x4*)pvsh;
    f32x4 a4 = p4[lane*2], b4 = p4[lane*2 + 1];
    f32x4 c4 = p4[128 + lane*2], d4 = p4[128 + lane*2 + 1];
    float pv[16];
    pv[0]=a4.x; pv[1]=a4.y; pv[2]=a4.z; pv[3]=a4.w;
    pv[4]=b4.x; pv[5]=b4.y; pv[6]=b4.z; pv[7]=b4.w;
    pv[8]=c4.x; pv[9]=c4.y; pv[10]=c4.z; pv[11]=c4.w;
    pv[12]=d4.x; pv[13]=d4.y; pv[14]=d4.z; pv[15]=d4.w;
    float cacc = 0.0f;
    #pragma unroll
    for (int r = 0; r < 8; ++r) {
      float su = fexp2(ureg[r]);
      #pragma unroll
      for (int j = 0; j < 8; ++j) {
        float pe = (float)ea[r][j];
        float e = 15.0f - flog2(pe);
        cacc += su * pv[j] * pe * e;
      }
      #pragma unroll
      for (int j = 0; j < 8; ++j) {
        float pe = (float)eb[r][j];
        float e = 15.0f - flog2(pe);
        cacc += su * pv[8 + j] * pe * e;
      }
    }
    #pragma unroll
    for (int off = 32; off; off >>= 1) cacc += __shfl_xor(cacc, off);
    if (lane == 0) sred[w] = cacc;
    __syncthreads();
    if (t == 0)
      atomicAdd(&cost[b], (sred[0]+sred[1]+sred[2]+sred[3]+sred[4]+sred[5]+
                           sred[6]+sred[7]) * INV_SCALE_F);
  }
}

extern "C" void kernel_launch(void* const* d_in, const int* in_sizes, int n_in,
                              void* d_out, int out_size, void* d_ws, size_t ws_size,
                              hipStream_t stream) {
  const float* x = (const float*)d_in[0];
  const float* y = (const float*)d_in[1];
  float* cost = (float*)d_out;

  char* base = (char*)d_ws;
  u16* Xn       = (u16*)base;                          // 8 MB
  u16* Yn       = (u16*)(base + 8388608);              // 8 MB
  u32* partials = (u32*)(base + 16777216);             // 532480 u32 ~= 2.03 MB
  size_t needed = 16777216 + (size_t)PWORDS * 4;
  if (ws_size < needed) return;                        // ~18.8 MB needed

  mfa_prep<<<256, 256, 0, stream>>>(x, y, Xn, Yn, partials, cost);

  (void)hipFuncSetAttribute((const void*)mfa_sink_fused,
                            hipFuncAttributeMaxDynamicSharedMemorySize, SMEM_TOTAL);
  mfa_sink_fused<<<dim3(256), dim3(512), SMEM_TOTAL, stream>>>(
      Xn, Yn, partials, cost);
}